// Round 11
// baseline (1849.354 us; speedup 1.0000x reference)
//
#include <hip/hip_runtime.h>
#include <stdint.h>

typedef _Float16 f16;
typedef _Float16 h2 __attribute__((ext_vector_type(2)));
typedef float f4 __attribute__((ext_vector_type(4)));

union F4H { f4 v; h2 h[4]; f16 s[8]; };

__device__ __forceinline__ float fdot2(h2 a, h2 b, float c) {
    return __builtin_amdgcn_fdot2(a, b, c, false);
}

#define NB 64
#define NT 512
#define NH 256
#define NG 1024

// ---------------- workspace layout ----------------
static const size_t OFF_H0   = 0;           // h0 f16  [64][512][256]   16,777,216 B
static const size_t OFF_X1   = 16777216;    // x1 f16  [64*512][1024]   67,108,864 B (role3 reuses dead rows for sWr)
static const size_t OFF_H1   = 83886080;    // h1 f16  [64][512][256]   16,777,216 B
static const size_t OFF_PL0  = 100663296;   // packed Whh0 [32][1024] f4  524,288 B
static const size_t OFF_PL1  = 101187584;   // packed Whh1                524,288 B
static const size_t OFF_WIH1 = 101711872;   // packed Wih1 [32][1024] f4  524,288 B
static const size_t OFF_WX0  = 102236160;   // wx0 h2 [4][1024]            16,384 B
static const size_t OFF_B0C  = 102252544;   // bias0c f32 [1024]            4,096 B
static const size_t OFF_B1C  = 102256640;   // bias1c f32 [1024]            4,096 B
static const size_t OFF_WR1  = 102260736;   // wr1p f4 [32][128]           65,536 B
static const size_t OFF_MM   = 102326272;   // mmean f32 [64][256]         65,536 B
static const size_t OFF_M1S  = 102391808;   // m1sum f32 [64][128]         32,768 B
static const size_t OFF_HL   = 102424576;   // hh1last f32 [64][128]       32,768 B
static const size_t OFF_FLG  = 102457344;   // flags u32 [3][64][16]       12,288 B (appended)

// ---------------- merged packing kernel ----------------
__device__ __forceinline__ void packw(const float* src, f4* dst, int id)
{
    const int j = id >> 5;
    const int g = id & 31;
    const float* s = src + j * 256 + g * 8;
    F4H u;
    #pragma unroll
    for (int i = 0; i < 8; ++i) u.s[i] = (f16)s[i];
    dst[g * 1024 + j] = u.v;
}

__global__ void pack_all(const float* __restrict__ Whh0, const float* __restrict__ Whh1,
                         const float* __restrict__ Wih1, const float* __restrict__ wih0,
                         const float* __restrict__ bih0, const float* __restrict__ bhh0,
                         const float* __restrict__ bih1, const float* __restrict__ bhh1,
                         const float* __restrict__ wr1,
                         f4* __restrict__ pl0, f4* __restrict__ pl1, f4* __restrict__ wih1p,
                         float* __restrict__ b0c, float* __restrict__ b1c,
                         h2* __restrict__ wx0p, f4* __restrict__ wr1p)
{
    const int id = blockIdx.x * 256 + threadIdx.x;   // 108544 tasks
    if (id < 32768) {
        packw(Whh0, pl0, id);
    } else if (id < 65536) {
        packw(Whh1, pl1, id - 32768);
    } else if (id < 98304) {
        packw(Wih1, wih1p, id - 65536);
    } else if (id < 99328) {
        const int j = id - 98304;
        b0c[j] = bih0[j] + bhh0[j];
    } else if (id < 100352) {
        const int j = id - 99328;
        b1c[j] = bih1[j] + bhh1[j];
    } else if (id < 104448) {
        const int q = id - 100352;
        const int p = q >> 10, j = q & 1023;
        h2 v; v[0] = (f16)wih0[j * 8 + 2 * p]; v[1] = (f16)wih0[j * 8 + 2 * p + 1];
        wx0p[p * 1024 + j] = v;
    } else {
        const int q = id - 104448;
        const int g = q >> 7, o = q & 127;
        F4H u;
        #pragma unroll
        for (int i = 0; i < 8; ++i)
            u.s[i] = (o < 100) ? (f16)wr1[o * 256 + g * 8 + i] : (f16)0.f;
        wr1p[g * 128 + o] = u.v;
    }
}

// ---------------- mega-kernel: 4-stage pipeline ----------------
// grid 256 x 512 thr, co-resident; roles of batch b (bids b, b+64, b+128, b+192)
// all on XCD b%8. Handoffs: role0->1->2 at CH=8; role2->3 at CH=16.
//   role 0: layer-0 chain, releases flag0 every 8 steps
//   role 1: chunked k2 GEMM (8 rows/chunk), releases flag1 per chunk
//   role 2: layer-1 chain, acquires flag1 every 8 steps; releases flag2 every
//           16 steps + final 513 after mmean
//   role 3: streams h1 chunks behind role 2 -> sWr_t = h1_t @ Wr1^T stored in
//           dead x1 rows; after flag2=513: mbase + elu reduction -> m1sum, hh1last
// Chain engine identical to r10: 3 LDS + 7 reg + 22 streamed (11 phases of 2).
#define DOT8(wa_, wb_, hh_) { F4H wa_u; wa_u.v = (wa_); F4H wb_u; wb_u.v = (wb_); F4H hh_u; hh_u.v = (hh_); \
    a0  = fdot2(wa_u.h[0], hh_u.h[0], a0 ); a1  = fdot2(wb_u.h[0], hh_u.h[0], a1 ); \
    a0b = fdot2(wa_u.h[1], hh_u.h[1], a0b); a1b = fdot2(wb_u.h[1], hh_u.h[1], a1b); \
    a0  = fdot2(wa_u.h[2], hh_u.h[2], a0 ); a1  = fdot2(wb_u.h[2], hh_u.h[2], a1 ); \
    a0b = fdot2(wa_u.h[3], hh_u.h[3], a0b); a1b = fdot2(wb_u.h[3], hh_u.h[3], a1b); }

#define STREAM_PHASES(HV) \
    _Pragma("unroll") \
    for (int p = 0; p < 11; ++p) { \
        if ((p & 1) == 0) { \
            DOT8(pA0[0], pA1[0], (HV)[10 + 2 * p]); \
            DOT8(pA0[1], pA1[1], (HV)[11 + 2 * p]); \
            if (p < 9) { \
                pA0[0] = str[(2 * (p + 2))     * 1024 + j0]; \
                pA1[0] = str[(2 * (p + 2))     * 1024 + j1]; \
                pA0[1] = str[(2 * (p + 2) + 1) * 1024 + j0]; \
                pA1[1] = str[(2 * (p + 2) + 1) * 1024 + j1]; \
            } \
        } else { \
            DOT8(pB0[0], pB1[0], (HV)[10 + 2 * p]); \
            DOT8(pB0[1], pB1[1], (HV)[11 + 2 * p]); \
            if (p < 9) { \
                pB0[0] = str[(2 * (p + 2))     * 1024 + j0]; \
                pB1[0] = str[(2 * (p + 2))     * 1024 + j1]; \
                pB0[1] = str[(2 * (p + 2) + 1) * 1024 + j0]; \
                pB1[1] = str[(2 * (p + 2) + 1) * 1024 + j1]; \
            } \
        } \
        if (p < 7) DOT8(wrA[p], wrB[p], (HV)[3 + p]); \
    }

__global__ __launch_bounds__(512)
void mega(const float* __restrict__ x,
          const f4* __restrict__ pl0, const f4* __restrict__ pl1,
          const f4* __restrict__ wih1p, const f4* __restrict__ wr1p,
          const float* __restrict__ b0c, const float* __restrict__ b1c,
          const float* __restrict__ Wl1, const float* __restrict__ b1,
          const h2* __restrict__ wx0p,
          f16* __restrict__ h0, f16* __restrict__ x1, f16* __restrict__ h1,
          float* __restrict__ mmean, float* __restrict__ m1sum,
          float* __restrict__ hh1last, unsigned int* __restrict__ flags)
{
    __shared__ f4 wlds[3 * 1024];                 // 48 KB
    __shared__ float gates[1024];                 // 4 KB
    __shared__ __align__(16) f16 hsh[256];        // 512 B
    __shared__ __align__(16) h2 xsh[512 * 4];     // 8 KB: role0 x; role1 h0 tile
    // total 61952 B -> 2-WG/CU plan -> 128-VGPR budget (r7/r10-calibrated)

    const int t = threadIdx.x;
    const int bid = blockIdx.x;
    const int role = bid >> 6;
    const int b = bid & 63;
    const int j0 = t, j1 = t + 512;

    if (role == 0) {
        // =================== layer-0 chain (producer) ===================
        const f4* pack = pl0;
        #pragma unroll
        for (int i = 0; i < 6; ++i) wlds[t + 512 * i] = pack[t + 512 * i];
        f4 wrA[7], wrB[7];
        #pragma unroll
        for (int g = 0; g < 7; ++g) {
            wrA[g] = pack[(3 + g) * 1024 + j0];
            wrB[g] = pack[(3 + g) * 1024 + j1];
        }
        const f4* str = pack + 10 * 1024;

        const float bc0 = b0c[j0], bc1 = b0c[j1];
        h2 wxA[4], wxB[4];
        #pragma unroll
        for (int p = 0; p < 4; ++p) { wxA[p] = wx0p[p * 1024 + j0]; wxB[p] = wx0p[p * 1024 + j1]; }
        const float* xb = x + ((size_t)b * NT + t) * 8;
        #pragma unroll
        for (int p = 0; p < 4; ++p) {
            h2 v; v[0] = (f16)xb[2 * p]; v[1] = (f16)xb[2 * p + 1];
            xsh[t * 4 + p] = v;
        }
        if (t < 32) { f4 zz = {0.f, 0.f, 0.f, 0.f}; ((f4*)hsh)[t] = zz; }
        float cst = 0.f;
        __syncthreads();

        f16* houtb = h0 + (size_t)b * NT * NH;
        unsigned int* myfl = flags + b * 16;

        #pragma unroll 1
        for (int tt = 0; tt < NT; ++tt) {
            f4 pA0[2], pA1[2], pB0[2], pB1[2];
            #pragma unroll
            for (int g = 0; g < 2; ++g) { pA0[g] = str[g * 1024 + j0]; pA1[g] = str[g * 1024 + j1]; }
            float a0 = bc0, a1 = bc1, a0b = 0.f, a1b = 0.f;
            #pragma unroll
            for (int p = 0; p < 4; ++p) {
                h2 xv = xsh[tt * 4 + p];
                a0 = fdot2(wxA[p], xv, a0);
                a1 = fdot2(wxB[p], xv, a1);
            }
            #pragma unroll
            for (int g = 0; g < 2; ++g) { pB0[g] = str[(2 + g) * 1024 + j0]; pB1[g] = str[(2 + g) * 1024 + j1]; }

            const f4* hv4 = (const f4*)hsh;
            #pragma unroll
            for (int i = 0; i < 3; ++i) DOT8(wlds[i * 1024 + j0], wlds[i * 1024 + j1], hv4[i]);
            STREAM_PHASES(hv4)

            gates[j0] = a0 + a0b;
            gates[j1] = a1 + a1b;
            __syncthreads();

            if (t < 256) {
                float gi = gates[t], gf = gates[t + 256], gg = gates[t + 512], go = gates[t + 768];
                float si = 1.f / (1.f + __expf(-gi));
                float sf = 1.f / (1.f + __expf(-gf));
                float so = 1.f / (1.f + __expf(-go));
                float tg = 1.f - 2.f / (__expf(2.f * gg) + 1.f);
                cst = sf * cst + si * tg;
                float th = 1.f - 2.f / (__expf(2.f * cst) + 1.f);
                float hvl = so * th;
                hsh[t] = (f16)hvl;
                houtb[(size_t)tt * NH + t] = (f16)hvl;
            }
            __syncthreads();   // drains vmcnt -> h0 chunk visible before release
            if (t == 0 && ((tt + 1) & 7) == 0)
                __hip_atomic_store(myfl, (unsigned)(tt + 1),
                                   __ATOMIC_RELEASE, __HIP_MEMORY_SCOPE_AGENT);
        }
    } else if (role == 1) {
        // ============ chunked k2 GEMM, 8 rows/chunk ============
        const float bc0 = b1c[j0], bc1 = b1c[j1];
        const f16* h0b = h0 + (size_t)b * NT * NH;
        f16* x1b = x1 + (size_t)b * NT * NG;
        const unsigned int* pfl = flags + b * 16;
        unsigned int* myfl = flags + 1024 + b * 16;
        f16* hrows = (f16*)xsh;    // [8][256] f16 = 4 KB
        bool dead = false;

        #pragma unroll 1
        for (int c = 0; c < 64; ++c) {
            if (t < 64 && !dead) {
                unsigned int guard = 0;
                while (__hip_atomic_load(pfl, __ATOMIC_ACQUIRE, __HIP_MEMORY_SCOPE_AGENT)
                       < (unsigned)((c + 1) * 8)) {
                    __builtin_amdgcn_s_sleep(8);
                    if (++guard > (1u << 16)) { dead = true; break; }
                }
            }
            __syncthreads();
            if (t < 256) {
                const int rr = t >> 5, cc = t & 31;
                ((f4*)hrows)[t] = ((const f4*)(h0b + (size_t)(c * 8 + rr) * NH))[cc];
            }
            __syncthreads();

            float acc0[8], acc1[8];
            #pragma unroll
            for (int r = 0; r < 8; ++r) { acc0[r] = bc0; acc1[r] = bc1; }

            f4 w0 = wih1p[j0], w1 = wih1p[j1];
            #pragma unroll 1
            for (int g = 0; g < 32; ++g) {
                f4 n0 = w0, n1 = w1;
                if (g < 31) { n0 = wih1p[(g + 1) * 1024 + j0]; n1 = wih1p[(g + 1) * 1024 + j1]; }
                F4H W0; W0.v = w0; F4H W1; W1.v = w1;
                #pragma unroll
                for (int r = 0; r < 8; ++r) {
                    F4H H; H.v = ((const f4*)hrows)[r * 32 + g];
                    acc0[r] = fdot2(W0.h[0], H.h[0], acc0[r]);
                    acc0[r] = fdot2(W0.h[1], H.h[1], acc0[r]);
                    acc0[r] = fdot2(W0.h[2], H.h[2], acc0[r]);
                    acc0[r] = fdot2(W0.h[3], H.h[3], acc0[r]);
                    acc1[r] = fdot2(W1.h[0], H.h[0], acc1[r]);
                    acc1[r] = fdot2(W1.h[1], H.h[1], acc1[r]);
                    acc1[r] = fdot2(W1.h[2], H.h[2], acc1[r]);
                    acc1[r] = fdot2(W1.h[3], H.h[3], acc1[r]);
                }
                w0 = n0; w1 = n1;
            }
            #pragma unroll
            for (int r = 0; r < 8; ++r) {
                x1b[(size_t)(c * 8 + r) * NG + j0] = (f16)acc0[r];
                x1b[(size_t)(c * 8 + r) * NG + j1] = (f16)acc1[r];
            }
            __syncthreads();
            if (t == 0) __hip_atomic_store(myfl, (unsigned)(c + 1),
                                           __ATOMIC_RELEASE, __HIP_MEMORY_SCOPE_AGENT);
        }
    } else if (role == 2) {
        // =================== layer-1 chain (consumer of x1) ===================
        const f4* pack = pl1;
        #pragma unroll
        for (int i = 0; i < 6; ++i) wlds[t + 512 * i] = pack[t + 512 * i];
        f4 wrA[7], wrB[7];
        #pragma unroll
        for (int g = 0; g < 7; ++g) {
            wrA[g] = pack[(3 + g) * 1024 + j0];
            wrB[g] = pack[(3 + g) * 1024 + j1];
        }
        const f4* str = pack + 10 * 1024;

        if (t < 32) { f4 zz = {0.f, 0.f, 0.f, 0.f}; ((f4*)hsh)[t] = zz; }
        float cst = 0.f, hsum = 0.f;
        __syncthreads();
        const f16* x1b = x1 + (size_t)b * NT * NG;
        f16* houtb = h1 + (size_t)b * NT * NH;
        const unsigned int* pfl = flags + 1024 + b * 16;
        unsigned int* myfl = flags + 2048 + b * 16;
        bool dead = false;

        #pragma unroll 1
        for (int tt = 0; tt < NT; ++tt) {
            if ((tt & 7) == 0) {                  // CH=8 acquire, one wave spins
                if (t < 64 && !dead) {
                    unsigned int guard = 0;
                    while (__hip_atomic_load(pfl, __ATOMIC_ACQUIRE, __HIP_MEMORY_SCOPE_AGENT)
                           < (unsigned)((tt >> 3) + 1)) {
                        __builtin_amdgcn_s_sleep(8);
                        if (++guard > (1u << 16)) { dead = true; break; }
                    }
                }
                __syncthreads();
            }

            f4 pA0[2], pA1[2], pB0[2], pB1[2];
            #pragma unroll
            for (int g = 0; g < 2; ++g) { pA0[g] = str[g * 1024 + j0]; pA1[g] = str[g * 1024 + j1]; }
            #pragma unroll
            for (int g = 0; g < 2; ++g) { pB0[g] = str[(2 + g) * 1024 + j0]; pB1[g] = str[(2 + g) * 1024 + j1]; }

            const f16* xr = x1b + (size_t)tt * NG;
            float a0 = (float)xr[j0];
            float a1 = (float)xr[j1];
            float a0b = 0.f, a1b = 0.f;

            const f4* hv4 = (const f4*)hsh;
            #pragma unroll
            for (int i = 0; i < 3; ++i) DOT8(wlds[i * 1024 + j0], wlds[i * 1024 + j1], hv4[i]);
            STREAM_PHASES(hv4)

            gates[j0] = a0 + a0b;
            gates[j1] = a1 + a1b;
            __syncthreads();

            if (t < 256) {
                float gi = gates[t], gf = gates[t + 256], gg = gates[t + 512], go = gates[t + 768];
                float si = 1.f / (1.f + __expf(-gi));
                float sf = 1.f / (1.f + __expf(-gf));
                float so = 1.f / (1.f + __expf(-go));
                float tg = 1.f - 2.f / (__expf(2.f * gg) + 1.f);
                cst = sf * cst + si * tg;
                float th = 1.f - 2.f / (__expf(2.f * cst) + 1.f);
                float hvl = so * th;
                hsh[t] = (f16)hvl;
                houtb[(size_t)tt * NH + t] = (f16)hvl;
                hsum += hvl;
            }
            __syncthreads();   // drains vmcnt -> h1 chunk visible before release
            if (t == 0 && ((tt + 1) & 15) == 0)
                __hip_atomic_store(myfl, (unsigned)(tt + 1),
                                   __ATOMIC_RELEASE, __HIP_MEMORY_SCOPE_AGENT);
        }
        if (t < 256) mmean[b * NH + t] = hsum * (1.f / 512.f);
        __syncthreads();       // drain mmean stores
        if (t == 0) __hip_atomic_store(myfl, 513u,
                                       __ATOMIC_RELEASE, __HIP_MEMORY_SCOPE_AGENT);
    } else {
        // =================== role 3: streamed k4a ===================
        // thread (o = t&127, q = t>>7): rows r ≡ q*4..q*4+3 (mod 16).
        const int o = t & 127;
        const int q = t >> 7;          // 0..3
        const f16* h1b = h1 + (size_t)b * NT * NH;
        f16* x1b = x1 + (size_t)b * NT * NG;
        const unsigned int* pfl = flags + 2048 + b * 16;
        bool dead = false;

        #pragma unroll 1
        for (int c = 0; c < 32; ++c) {
            if (t < 64 && !dead) {
                unsigned int guard = 0;
                while (__hip_atomic_load(pfl, __ATOMIC_ACQUIRE, __HIP_MEMORY_SCOPE_AGENT)
                       < (unsigned)((c + 1) * 16)) {
                    __builtin_amdgcn_s_sleep(8);
                    if (++guard > (1u << 20)) { dead = true; break; }
                }
            }
            __syncthreads();
            #pragma unroll 1
            for (int i = 0; i < 4; ++i) {
                const int row = c * 16 + q * 4 + i;
                float acc = 0.f;
                const f4* hr = (const f4*)(h1b + (size_t)row * NH);
                #pragma unroll 4
                for (int g = 0; g < 32; ++g) {
                    F4H H; H.v = hr[g];
                    F4H W; W.v = wr1p[g * 128 + o];
                    acc = fdot2(W.h[0], H.h[0], acc);
                    acc = fdot2(W.h[1], H.h[1], acc);
                    acc = fdot2(W.h[2], H.h[2], acc);
                    acc = fdot2(W.h[3], H.h[3], acc);
                }
                ((float*)(x1b + (size_t)row * NG))[o] = acc;   // dead x1 row reuse
            }
        }
        // final: wait role-2 completion (mmean visible), mbase + elu reduction
        if (t < 64 && !dead) {
            unsigned int guard = 0;
            while (__hip_atomic_load(pfl, __ATOMIC_ACQUIRE, __HIP_MEMORY_SCOPE_AGENT) < 513u) {
                __builtin_amdgcn_s_sleep(8);
                if (++guard > (1u << 20)) { dead = true; break; }
            }
        }
        __syncthreads();
        float* pool = (float*)wlds;    // msh[0:256], mbase[256:384], red[384:896]
        if (t < 256) pool[t] = mmean[b * NH + t];
        __syncthreads();
        if (t < 128) {
            float a = 0.f;
            if (t < 100) {
                a = b1[t];
                const float* wrow = Wl1 + t * 256;
                #pragma unroll 4
                for (int j = 0; j < 256; ++j) a += pool[j] * wrow[j];
            }
            pool[256 + t] = a;
        }
        __syncthreads();
        const float mb = pool[256 + o];
        float sum = 0.f, last = 0.f;
        #pragma unroll 1
        for (int c2 = 0; c2 < 32; ++c2) {
            #pragma unroll
            for (int i = 0; i < 4; ++i) {
                const int row = c2 * 16 + q * 4 + i;
                float s = mb + ((const float*)(x1b + (size_t)row * NG))[o];
                float e = s > 0.f ? s : (__expf(s) - 1.f);
                sum += e;
                if (row == 511) last = e;
            }
        }
        pool[384 + q * 128 + o] = sum;
        __syncthreads();
        if (q == 0)
            m1sum[b * 128 + o] = pool[384 + o] + pool[512 + o] + pool[640 + o] + pool[768 + o];
        if (q == 3)
            hh1last[b * 128 + o] = last;
    }
}

// ---------------- K4b: final head (proven) ----------------
__global__ __launch_bounds__(128)
void k4b(const float* __restrict__ m1sum, const float* __restrict__ hh1last,
         const float* __restrict__ Wl2, const float* __restrict__ Wr2,
         const float* __restrict__ b2,
         const float* __restrict__ Wfc1, const float* __restrict__ bfc1,
         const float* __restrict__ Wfc2, const float* __restrict__ bfc2,
         float* __restrict__ out)
{
    __shared__ float m1s[128];
    __shared__ float hl[128];
    __shared__ float s[128];
    __shared__ float zsh[512];
    const int b = blockIdx.x;
    const int l = threadIdx.x;

    m1s[l] = m1sum[b * 128 + l] * (1.f / 512.f);
    hl[l] = hh1last[b * 128 + l];
    __syncthreads();

    {
        float acc = b2[l];
        const float* wl2r = Wl2 + l * 100;
        const float* wr2r = Wr2 + l * 100;
        for (int j = 0; j < 100; ++j) acc += m1s[j] * wl2r[j] + hl[j] * wr2r[j];
        s[l] = acc;
    }
    __syncthreads();

    #pragma unroll 1
    for (int i = 0; i < 4; ++i) {
        const int idx = l + 128 * i;
        const int k = idx >> 6, o = idx & 63;
        const float* w = Wfc1 + (size_t)(k * 64 + o) * 128;
        float a = bfc1[k * 64 + o];
        for (int d = 0; d < 128; ++d) a += s[d] * w[d];
        zsh[idx] = a > 0.f ? a : 0.f;
    }
    __syncthreads();

    #pragma unroll 1
    for (int i = 0; i < 2; ++i) {
        const int idx = l + 128 * i;
        if (idx < 192) {
            const int k = idx / 24, p = idx % 24;
            const float* w = Wfc2 + (size_t)(k * 24 + p) * 64;
            float a = bfc2[k * 24 + p];
            const float* z = zsh + k * 64;
            for (int d = 0; d < 64; ++d) a += z[d] * w[d];
            out[(size_t)(k * 64 + b) * 24 + p] = a;
        }
    }
}

// ---------------- launch ----------------
extern "C" void kernel_launch(void* const* d_in, const int* in_sizes, int n_in,
                              void* d_out, int out_size, void* d_ws, size_t ws_size,
                              hipStream_t stream)
{
    const float* x    = (const float*)d_in[0];
    const float* Wih0 = (const float*)d_in[1];
    const float* Whh0 = (const float*)d_in[2];
    const float* bih0 = (const float*)d_in[3];
    const float* bhh0 = (const float*)d_in[4];
    const float* Wih1 = (const float*)d_in[5];
    const float* Whh1 = (const float*)d_in[6];
    const float* bih1 = (const float*)d_in[7];
    const float* bhh1 = (const float*)d_in[8];
    const float* Wl1  = (const float*)d_in[9];
    const float* Wr1  = (const float*)d_in[10];
    const float* b1   = (const float*)d_in[11];
    const float* Wl2  = (const float*)d_in[12];
    const float* Wr2  = (const float*)d_in[13];
    const float* b2   = (const float*)d_in[14];
    const float* Wfc1 = (const float*)d_in[15];
    const float* bfc1 = (const float*)d_in[16];
    const float* Wfc2 = (const float*)d_in[17];
    const float* bfc2 = (const float*)d_in[18];

    char* ws = (char*)d_ws;
    f16*   h0f   = (f16*)(ws + OFF_H0);
    f16*   x1f   = (f16*)(ws + OFF_X1);
    f16*   h1f   = (f16*)(ws + OFF_H1);
    f4*    pl0   = (f4*)(ws + OFF_PL0);
    f4*    pl1   = (f4*)(ws + OFF_PL1);
    f4*    wih1p = (f4*)(ws + OFF_WIH1);
    h2*    wx0p  = (h2*)(ws + OFF_WX0);
    float* b0c   = (float*)(ws + OFF_B0C);
    float* b1c   = (float*)(ws + OFF_B1C);
    f4*    wr1p  = (f4*)(ws + OFF_WR1);
    float* mm    = (float*)(ws + OFF_MM);
    float* m1s   = (float*)(ws + OFF_M1S);
    float* hhl   = (float*)(ws + OFF_HL);
    unsigned int* flg = (unsigned int*)(ws + OFF_FLG);

    pack_all<<<424, 256, 0, stream>>>(Whh0, Whh1, Wih1, Wih0,
                                      bih0, bhh0, bih1, bhh1, Wr1,
                                      pl0, pl1, wih1p, b0c, b1c, wx0p, wr1p);
    hipMemsetAsync(flg, 0, 12288, stream);

    // 4-role pipeline: chain0 -> k2 -> chain1 -> k4a, one launch, 256 WGs
    mega<<<256, 512, 0, stream>>>(x, pl0, pl1, wih1p, wr1p, b0c, b1c, Wl1, b1,
                                  wx0p, h0f, x1f, h1f, mm, m1s, hhl, flg);

    k4b<<<64, 128, 0, stream>>>(m1s, hhl, Wl2, Wr2, b2, Wfc1, bfc1, Wfc2, bfc2, (float*)d_out);
}

// Round 12
// 1339.921 us; speedup vs baseline: 1.3802x; 1.3802x over previous
//
#include <hip/hip_runtime.h>
#include <stdint.h>

typedef _Float16 f16;
typedef _Float16 h2 __attribute__((ext_vector_type(2)));
typedef float f4 __attribute__((ext_vector_type(4)));

union F4H { f4 v; h2 h[4]; f16 s[8]; };

__device__ __forceinline__ float fdot2(h2 a, h2 b, float c) {
    return __builtin_amdgcn_fdot2(a, b, c, false);
}

#define NB 64
#define NT 512
#define NH 256
#define NG 1024

// ---------------- workspace layout (r7 footprint) ----------------
static const size_t OFF_H0   = 0;           // h0 f16  [64][512][256]   16,777,216 B
static const size_t OFF_X1   = 16777216;    // x1 f16  [64*512][1024]   67,108,864 B
static const size_t OFF_H1   = 83886080;    // h1 f16  [64][512][256]   16,777,216 B
static const size_t OFF_PL0  = 100663296;   // packed Whh0 [32][1024] f4  524,288 B
static const size_t OFF_PL1  = 101187584;   // packed Whh1                524,288 B
static const size_t OFF_WIH1 = 101711872;   // packed Wih1 [32][1024] f4  524,288 B
static const size_t OFF_WX0  = 102236160;   // wx0 h2 [4][1024]            16,384 B
static const size_t OFF_B0C  = 102252544;   // bias0c f32 [1024]            4,096 B
static const size_t OFF_B1C  = 102256640;   // bias1c f32 [1024]            4,096 B
static const size_t OFF_WR1  = 102260736;   // wr1p f4 [32][128]           65,536 B
static const size_t OFF_MM   = 102326272;   // mmean f32 [64][256]         65,536 B
static const size_t OFF_M1S  = 102391808;   // m1sum f32 [64][128]         32,768 B
static const size_t OFF_HL   = 102424576;   // hh1last f32 (k4a, AFTER mega)
static const size_t OFF_FLG  = OFF_HL;      // flags alias hh1last (dead until k4a)

// ---------------- merged packing kernel ----------------
__device__ __forceinline__ void packw(const float* src, f4* dst, int id)
{
    const int j = id >> 5;
    const int g = id & 31;
    const float* s = src + j * 256 + g * 8;
    F4H u;
    #pragma unroll
    for (int i = 0; i < 8; ++i) u.s[i] = (f16)s[i];
    dst[g * 1024 + j] = u.v;
}

__global__ void pack_all(const float* __restrict__ Whh0, const float* __restrict__ Whh1,
                         const float* __restrict__ Wih1, const float* __restrict__ wih0,
                         const float* __restrict__ bih0, const float* __restrict__ bhh0,
                         const float* __restrict__ bih1, const float* __restrict__ bhh1,
                         const float* __restrict__ wr1,
                         f4* __restrict__ pl0, f4* __restrict__ pl1, f4* __restrict__ wih1p,
                         float* __restrict__ b0c, float* __restrict__ b1c,
                         h2* __restrict__ wx0p, f4* __restrict__ wr1p)
{
    const int id = blockIdx.x * 256 + threadIdx.x;   // 108544 tasks
    if (id < 32768) {
        packw(Whh0, pl0, id);
    } else if (id < 65536) {
        packw(Whh1, pl1, id - 32768);
    } else if (id < 98304) {
        packw(Wih1, wih1p, id - 65536);
    } else if (id < 99328) {
        const int j = id - 98304;
        b0c[j] = bih0[j] + bhh0[j];
    } else if (id < 100352) {
        const int j = id - 99328;
        b1c[j] = bih1[j] + bhh1[j];
    } else if (id < 104448) {
        const int q = id - 100352;
        const int p = q >> 10, j = q & 1023;
        h2 v; v[0] = (f16)wih0[j * 8 + 2 * p]; v[1] = (f16)wih0[j * 8 + 2 * p + 1];
        wx0p[p * 1024 + j] = v;
    } else {
        const int q = id - 104448;
        const int g = q >> 7, o = q & 127;
        F4H u;
        #pragma unroll
        for (int i = 0; i < 8; ++i)
            u.s[i] = (o < 100) ? (f16)wr1[o * 256 + g * 8 + i] : (f16)0.f;
        wr1p[g * 128 + o] = u.v;
    }
}

// ---------------- mega-kernel: 3-stage pipeline, CH=16 (r7 structure) ----------------
// k-split: groups 0-2 LDS, 3-9 registers (7 groups, 56 VGPR), 10-31 streamed in
// 11 double-buffered phases of 2 (32 VGPR buffers). Ledger 88+misc fits 128.
#define DOT8(wa_, wb_, hh_) { F4H wa_u; wa_u.v = (wa_); F4H wb_u; wb_u.v = (wb_); F4H hh_u; hh_u.v = (hh_); \
    a0  = fdot2(wa_u.h[0], hh_u.h[0], a0 ); a1  = fdot2(wb_u.h[0], hh_u.h[0], a1 ); \
    a0b = fdot2(wa_u.h[1], hh_u.h[1], a0b); a1b = fdot2(wb_u.h[1], hh_u.h[1], a1b); \
    a0  = fdot2(wa_u.h[2], hh_u.h[2], a0 ); a1  = fdot2(wb_u.h[2], hh_u.h[2], a1 ); \
    a0b = fdot2(wa_u.h[3], hh_u.h[3], a0b); a1b = fdot2(wb_u.h[3], hh_u.h[3], a1b); }

#define STREAM_PHASES(HV) \
    _Pragma("unroll") \
    for (int p = 0; p < 11; ++p) { \
        if ((p & 1) == 0) { \
            DOT8(pA0[0], pA1[0], (HV)[10 + 2 * p]); \
            DOT8(pA0[1], pA1[1], (HV)[11 + 2 * p]); \
            if (p < 9) { \
                pA0[0] = str[(2 * (p + 2))     * 1024 + j0]; \
                pA1[0] = str[(2 * (p + 2))     * 1024 + j1]; \
                pA0[1] = str[(2 * (p + 2) + 1) * 1024 + j0]; \
                pA1[1] = str[(2 * (p + 2) + 1) * 1024 + j1]; \
            } \
        } else { \
            DOT8(pB0[0], pB1[0], (HV)[10 + 2 * p]); \
            DOT8(pB0[1], pB1[1], (HV)[11 + 2 * p]); \
            if (p < 9) { \
                pB0[0] = str[(2 * (p + 2))     * 1024 + j0]; \
                pB1[0] = str[(2 * (p + 2))     * 1024 + j1]; \
                pB0[1] = str[(2 * (p + 2) + 1) * 1024 + j0]; \
                pB1[1] = str[(2 * (p + 2) + 1) * 1024 + j1]; \
            } \
        } \
        if (p < 7) DOT8(wrA[p], wrB[p], (HV)[3 + p]); \
    }

__global__ __launch_bounds__(512)
void mega(const float* __restrict__ x,
          const f4* __restrict__ pl0, const f4* __restrict__ pl1,
          const f4* __restrict__ wih1p,
          const float* __restrict__ b0c, const float* __restrict__ b1c,
          const h2* __restrict__ wx0p,
          f16* __restrict__ h0, f16* __restrict__ x1, f16* __restrict__ h1,
          float* __restrict__ mmean, unsigned int* __restrict__ flags)
{
    __shared__ f4 wlds[3 * 1024];                 // 48 KB (chain roles)
    __shared__ float gates[1024];                 // 4 KB
    __shared__ __align__(16) f16 hsh[256];        // 512 B
    __shared__ __align__(16) h2 xsh[512 * 4];     // 8 KB: role0 x frags; role1 h0 tile
    // total 61952 B -> 2-WG/CU plan -> 128-VGPR budget (r7-calibrated)

    const int t = threadIdx.x;
    const int bid = blockIdx.x;
    const int role = bid >> 6;
    const int b = bid & 63;
    const int j0 = t, j1 = t + 512;

    if (role == 0) {
        // =================== layer-0 chain (producer) ===================
        const f4* pack = pl0;
        #pragma unroll
        for (int i = 0; i < 6; ++i) wlds[t + 512 * i] = pack[t + 512 * i];
        f4 wrA[7], wrB[7];
        #pragma unroll
        for (int g = 0; g < 7; ++g) {
            wrA[g] = pack[(3 + g) * 1024 + j0];
            wrB[g] = pack[(3 + g) * 1024 + j1];
        }
        const f4* str = pack + 10 * 1024;

        const float bc0 = b0c[j0], bc1 = b0c[j1];
        h2 wxA[4], wxB[4];
        #pragma unroll
        for (int p = 0; p < 4; ++p) { wxA[p] = wx0p[p * 1024 + j0]; wxB[p] = wx0p[p * 1024 + j1]; }
        const float* xb = x + ((size_t)b * NT + t) * 8;
        #pragma unroll
        for (int p = 0; p < 4; ++p) {
            h2 v; v[0] = (f16)xb[2 * p]; v[1] = (f16)xb[2 * p + 1];
            xsh[t * 4 + p] = v;
        }
        if (t < 32) { f4 zz = {0.f, 0.f, 0.f, 0.f}; ((f4*)hsh)[t] = zz; }
        float cst = 0.f;
        __syncthreads();

        f16* houtb = h0 + (size_t)b * NT * NH;
        unsigned int* myfl = flags + b * 16;

        #pragma unroll 1
        for (int tt = 0; tt < NT; ++tt) {
            f4 pA0[2], pA1[2], pB0[2], pB1[2];
            #pragma unroll
            for (int g = 0; g < 2; ++g) { pA0[g] = str[g * 1024 + j0]; pA1[g] = str[g * 1024 + j1]; }
            float a0 = bc0, a1 = bc1, a0b = 0.f, a1b = 0.f;
            #pragma unroll
            for (int p = 0; p < 4; ++p) {
                h2 xv = xsh[tt * 4 + p];
                a0 = fdot2(wxA[p], xv, a0);
                a1 = fdot2(wxB[p], xv, a1);
            }
            #pragma unroll
            for (int g = 0; g < 2; ++g) { pB0[g] = str[(2 + g) * 1024 + j0]; pB1[g] = str[(2 + g) * 1024 + j1]; }

            const f4* hv4 = (const f4*)hsh;
            #pragma unroll
            for (int i = 0; i < 3; ++i) DOT8(wlds[i * 1024 + j0], wlds[i * 1024 + j1], hv4[i]);
            STREAM_PHASES(hv4)

            gates[j0] = a0 + a0b;
            gates[j1] = a1 + a1b;
            __syncthreads();

            if (t < 256) {
                float gi = gates[t], gf = gates[t + 256], gg = gates[t + 512], go = gates[t + 768];
                float si = 1.f / (1.f + __expf(-gi));
                float sf = 1.f / (1.f + __expf(-gf));
                float so = 1.f / (1.f + __expf(-go));
                float tg = 1.f - 2.f / (__expf(2.f * gg) + 1.f);
                cst = sf * cst + si * tg;
                float th = 1.f - 2.f / (__expf(2.f * cst) + 1.f);
                float hvl = so * th;
                hsh[t] = (f16)hvl;
                houtb[(size_t)tt * NH + t] = (f16)hvl;
            }
            __syncthreads();   // drains vmcnt -> h0 chunk visible before release
            if (t == 0 && ((tt + 1) & 15) == 0)
                __hip_atomic_store(myfl, (unsigned)(tt + 1),
                                   __ATOMIC_RELEASE, __HIP_MEMORY_SCOPE_AGENT);
        }
    } else if (role == 1) {
        // ============ chunked k2 GEMM (r7-proven, unchanged) ============
        const float bc0 = b1c[j0], bc1 = b1c[j1];
        const f16* h0b = h0 + (size_t)b * NT * NH;
        f16* x1b = x1 + (size_t)b * NT * NG;
        const unsigned int* pfl = flags + b * 16;
        unsigned int* myfl = flags + 1024 + b * 16;
        f16* hrows = (f16*)xsh;    // [16][256] f16 = 8 KB
        bool dead = false;

        #pragma unroll 1
        for (int c = 0; c < 32; ++c) {
            if (t < 64 && !dead) {
                unsigned int guard = 0;
                while (__hip_atomic_load(pfl, __ATOMIC_ACQUIRE, __HIP_MEMORY_SCOPE_AGENT)
                       < (unsigned)((c + 1) * 16)) {
                    __builtin_amdgcn_s_sleep(8);
                    if (++guard > (1u << 16)) { dead = true; break; }
                }
            }
            __syncthreads();
            {
                const int rr = t >> 5, cc = t & 31;
                ((f4*)hrows)[t] = ((const f4*)(h0b + (size_t)(c * 16 + rr) * NH))[cc];
            }
            __syncthreads();

            float acc0[16], acc1[16];
            #pragma unroll
            for (int r = 0; r < 16; ++r) { acc0[r] = bc0; acc1[r] = bc1; }

            f4 w0 = wih1p[j0], w1 = wih1p[j1];
            #pragma unroll 1
            for (int g = 0; g < 32; ++g) {
                f4 n0 = w0, n1 = w1;
                if (g < 31) { n0 = wih1p[(g + 1) * 1024 + j0]; n1 = wih1p[(g + 1) * 1024 + j1]; }
                F4H W0; W0.v = w0; F4H W1; W1.v = w1;
                #pragma unroll
                for (int r = 0; r < 16; ++r) {
                    F4H H; H.v = ((const f4*)hrows)[r * 32 + g];
                    acc0[r] = fdot2(W0.h[0], H.h[0], acc0[r]);
                    acc0[r] = fdot2(W0.h[1], H.h[1], acc0[r]);
                    acc0[r] = fdot2(W0.h[2], H.h[2], acc0[r]);
                    acc0[r] = fdot2(W0.h[3], H.h[3], acc0[r]);
                    acc1[r] = fdot2(W1.h[0], H.h[0], acc1[r]);
                    acc1[r] = fdot2(W1.h[1], H.h[1], acc1[r]);
                    acc1[r] = fdot2(W1.h[2], H.h[2], acc1[r]);
                    acc1[r] = fdot2(W1.h[3], H.h[3], acc1[r]);
                }
                w0 = n0; w1 = n1;
            }
            #pragma unroll
            for (int r = 0; r < 16; ++r) {
                x1b[(size_t)(c * 16 + r) * NG + j0] = (f16)acc0[r];
                x1b[(size_t)(c * 16 + r) * NG + j1] = (f16)acc1[r];
            }
            __syncthreads();
            if (t == 0) __hip_atomic_store(myfl, (unsigned)(c + 1),
                                           __ATOMIC_RELEASE, __HIP_MEMORY_SCOPE_AGENT);
        }
    } else {
        // =================== layer-1 chain (consumer of x1) ===================
        const f4* pack = pl1;
        #pragma unroll
        for (int i = 0; i < 6; ++i) wlds[t + 512 * i] = pack[t + 512 * i];
        f4 wrA[7], wrB[7];
        #pragma unroll
        for (int g = 0; g < 7; ++g) {
            wrA[g] = pack[(3 + g) * 1024 + j0];
            wrB[g] = pack[(3 + g) * 1024 + j1];
        }
        const f4* str = pack + 10 * 1024;

        if (t < 32) { f4 zz = {0.f, 0.f, 0.f, 0.f}; ((f4*)hsh)[t] = zz; }
        float cst = 0.f, hsum = 0.f;
        __syncthreads();
        const f16* x1b = x1 + (size_t)b * NT * NG;
        f16* houtb = h1 + (size_t)b * NT * NH;
        const unsigned int* pfl = flags + 1024 + b * 16;
        bool dead = false;

        #pragma unroll 1
        for (int tt = 0; tt < NT; ++tt) {
            if ((tt & 15) == 0) {                 // chunk-grained acquire, one wave spins
                if (t < 64 && !dead) {
                    unsigned int guard = 0;
                    while (__hip_atomic_load(pfl, __ATOMIC_ACQUIRE, __HIP_MEMORY_SCOPE_AGENT)
                           < (unsigned)((tt >> 4) + 1)) {
                        __builtin_amdgcn_s_sleep(8);
                        if (++guard > (1u << 16)) { dead = true; break; }
                    }
                }
                __syncthreads();
            }

            f4 pA0[2], pA1[2], pB0[2], pB1[2];
            #pragma unroll
            for (int g = 0; g < 2; ++g) { pA0[g] = str[g * 1024 + j0]; pA1[g] = str[g * 1024 + j1]; }
            #pragma unroll
            for (int g = 0; g < 2; ++g) { pB0[g] = str[(2 + g) * 1024 + j0]; pB1[g] = str[(2 + g) * 1024 + j1]; }

            const f16* xr = x1b + (size_t)tt * NG;
            float a0 = (float)xr[j0];
            float a1 = (float)xr[j1];
            float a0b = 0.f, a1b = 0.f;

            const f4* hv4 = (const f4*)hsh;
            #pragma unroll
            for (int i = 0; i < 3; ++i) DOT8(wlds[i * 1024 + j0], wlds[i * 1024 + j1], hv4[i]);
            STREAM_PHASES(hv4)

            gates[j0] = a0 + a0b;
            gates[j1] = a1 + a1b;
            __syncthreads();

            if (t < 256) {
                float gi = gates[t], gf = gates[t + 256], gg = gates[t + 512], go = gates[t + 768];
                float si = 1.f / (1.f + __expf(-gi));
                float sf = 1.f / (1.f + __expf(-gf));
                float so = 1.f / (1.f + __expf(-go));
                float tg = 1.f - 2.f / (__expf(2.f * gg) + 1.f);
                cst = sf * cst + si * tg;
                float th = 1.f - 2.f / (__expf(2.f * cst) + 1.f);
                float hvl = so * th;
                hsh[t] = (f16)hvl;
                houtb[(size_t)tt * NH + t] = (f16)hvl;
                hsum += hvl;
            }
            __syncthreads();
        }
        if (t < 256) mmean[b * NH + t] = hsum * (1.f / 512.f);
    }
}

// ---------------- K4a (proven) ----------------
__global__ __launch_bounds__(256)
void k4a(const f16* __restrict__ h1, const float* __restrict__ mmean,
         const float* __restrict__ Wl1, const float* __restrict__ b1,
         const f4* __restrict__ wr1p, float* __restrict__ m1sum,
         float* __restrict__ hh1last)
{
    __shared__ __align__(16) f16 ash[64 * 256];
    __shared__ float msh[256];
    __shared__ float mbase[128];
    __shared__ float red[256];
    const int l = threadIdx.x;
    const int b = blockIdx.x >> 3;
    const int ch = blockIdx.x & 7;

    const f4* src = (const f4*)(h1 + ((size_t)b * 512 + ch * 64) * 256);
    f4* dst = (f4*)ash;
    #pragma unroll
    for (int i = 0; i < 8; ++i) dst[l + 256 * i] = src[l + 256 * i];
    msh[l] = mmean[b * 256 + l];
    __syncthreads();

    if (l < 128) {
        float acc = 0.f;
        if (l < 100) {
            acc = b1[l];
            const float* wrow = Wl1 + l * 256;
            for (int j = 0; j < 256; ++j) acc += msh[j] * wrow[j];
        }
        mbase[l] = acc;
    }
    __syncthreads();

    const int o = l & 127;
    const int th = l >> 7;
    float sumloc = 0.f;
    float last = 0.f;
    #pragma unroll 1
    for (int it = 0; it < 32; ++it) {
        const int tloc = it * 2 + th;
        float acc = mbase[o];
        const f4* arow = (const f4*)(ash + tloc * 256);
        #pragma unroll
        for (int u = 0; u < 32; ++u) {
            F4H av; av.v = arow[u];
            F4H wv; wv.v = wr1p[u * 128 + o];
            #pragma unroll
            for (int p = 0; p < 4; ++p) acc = fdot2(av.h[p], wv.h[p], acc);
        }
        float e = acc > 0.f ? acc : (__expf(acc) - 1.f);
        sumloc += e;
        if (tloc == 63) last = e;
    }
    red[l] = sumloc;
    __syncthreads();
    if (l < 128) {
        float s = red[l] + red[l + 128];
        if (l < 100) atomicAdd(m1sum + b * 128 + l, s);
    }
    if (ch == 7 && th == 1) hh1last[b * 128 + o] = last;
}

// ---------------- K4b: final head (proven) ----------------
__global__ __launch_bounds__(128)
void k4b(const float* __restrict__ m1sum, const float* __restrict__ hh1last,
         const float* __restrict__ Wl2, const float* __restrict__ Wr2,
         const float* __restrict__ b2,
         const float* __restrict__ Wfc1, const float* __restrict__ bfc1,
         const float* __restrict__ Wfc2, const float* __restrict__ bfc2,
         float* __restrict__ out)
{
    __shared__ float m1s[128];
    __shared__ float hl[128];
    __shared__ float s[128];
    __shared__ float zsh[512];
    const int b = blockIdx.x;
    const int l = threadIdx.x;

    m1s[l] = m1sum[b * 128 + l] * (1.f / 512.f);
    hl[l] = hh1last[b * 128 + l];
    __syncthreads();

    {
        float acc = b2[l];
        const float* wl2r = Wl2 + l * 100;
        const float* wr2r = Wr2 + l * 100;
        for (int j = 0; j < 100; ++j) acc += m1s[j] * wl2r[j] + hl[j] * wr2r[j];
        s[l] = acc;
    }
    __syncthreads();

    #pragma unroll 1
    for (int i = 0; i < 4; ++i) {
        const int idx = l + 128 * i;
        const int k = idx >> 6, o = idx & 63;
        const float* w = Wfc1 + (size_t)(k * 64 + o) * 128;
        float a = bfc1[k * 64 + o];
        for (int d = 0; d < 128; ++d) a += s[d] * w[d];
        zsh[idx] = a > 0.f ? a : 0.f;
    }
    __syncthreads();

    #pragma unroll 1
    for (int i = 0; i < 2; ++i) {
        const int idx = l + 128 * i;
        if (idx < 192) {
            const int k = idx / 24, p = idx % 24;
            const float* w = Wfc2 + (size_t)(k * 24 + p) * 64;
            float a = bfc2[k * 24 + p];
            const float* z = zsh + k * 64;
            for (int d = 0; d < 64; ++d) a += z[d] * w[d];
            out[(size_t)(k * 64 + b) * 24 + p] = a;
        }
    }
}

// ---------------- launch ----------------
extern "C" void kernel_launch(void* const* d_in, const int* in_sizes, int n_in,
                              void* d_out, int out_size, void* d_ws, size_t ws_size,
                              hipStream_t stream)
{
    const float* x    = (const float*)d_in[0];
    const float* Wih0 = (const float*)d_in[1];
    const float* Whh0 = (const float*)d_in[2];
    const float* bih0 = (const float*)d_in[3];
    const float* bhh0 = (const float*)d_in[4];
    const float* Wih1 = (const float*)d_in[5];
    const float* Whh1 = (const float*)d_in[6];
    const float* bih1 = (const float*)d_in[7];
    const float* bhh1 = (const float*)d_in[8];
    const float* Wl1  = (const float*)d_in[9];
    const float* Wr1  = (const float*)d_in[10];
    const float* b1   = (const float*)d_in[11];
    const float* Wl2  = (const float*)d_in[12];
    const float* Wr2  = (const float*)d_in[13];
    const float* b2   = (const float*)d_in[14];
    const float* Wfc1 = (const float*)d_in[15];
    const float* bfc1 = (const float*)d_in[16];
    const float* Wfc2 = (const float*)d_in[17];
    const float* bfc2 = (const float*)d_in[18];

    char* ws = (char*)d_ws;
    f16*   h0f   = (f16*)(ws + OFF_H0);
    f16*   x1f   = (f16*)(ws + OFF_X1);
    f16*   h1f   = (f16*)(ws + OFF_H1);
    f4*    pl0   = (f4*)(ws + OFF_PL0);
    f4*    pl1   = (f4*)(ws + OFF_PL1);
    f4*    wih1p = (f4*)(ws + OFF_WIH1);
    h2*    wx0p  = (h2*)(ws + OFF_WX0);
    float* b0c   = (float*)(ws + OFF_B0C);
    float* b1c   = (float*)(ws + OFF_B1C);
    f4*    wr1p  = (f4*)(ws + OFF_WR1);
    float* mm    = (float*)(ws + OFF_MM);
    float* m1s   = (float*)(ws + OFF_M1S);
    float* hhl   = (float*)(ws + OFF_HL);
    unsigned int* flg = (unsigned int*)(ws + OFF_FLG);

    pack_all<<<424, 256, 0, stream>>>(Whh0, Whh1, Wih1, Wih0,
                                      bih0, bhh0, bih1, bhh1, Wr1,
                                      pl0, pl1, wih1p, b0c, b1c, wx0p, wr1p);
    hipMemsetAsync(m1s, 0, 64 * 128 * sizeof(float), stream);
    hipMemsetAsync(flg, 0, 8192, stream);

    // pipelined chain0 -> k2 -> chain1, one launch, 192 co-resident WGs
    mega<<<192, 512, 0, stream>>>(x, pl0, pl1, wih1p, b0c, b1c, wx0p,
                                  h0f, x1f, h1f, mm, flg);

    k4a<<<512, 256, 0, stream>>>(h1f, mm, Wl1, b1, wr1p, m1s, hhl);
    k4b<<<64, 128, 0, stream>>>(m1s, hhl, Wl2, Wr2, b2, Wfc1, bfc1, Wfc2, bfc2, (float*)d_out);
}